// Round 4
// baseline (128.634 us; speedup 1.0000x reference)
//
#include <hip/hip_runtime.h>

// out = A @ x, COO (rows sorted), E=800000, N=50000, D=128.
// R12: XCD-L2-resident dim-sliced gather.
// R11 counters: agg 46 us, VALUBusy 15.9%, FETCH 74.4 MB (compulsory ~19 MB)
// -> random 256 B row-gathers miss the 4 MiB per-XCD L2 (12.8 MB table) and
// are served by L3/fabric; PF 8->16 (true 16 in flight) changed nothing, so
// the limiter is L2-miss latency, not per-wave MLP.
// Fix: split D=128 into 4 slices of 32 dims (64 B/row). Slice table = 3.2 MB
// fits one XCD L2. slice = blockIdx.x & 3 pins slice s to XCDs {s, s+4}
// (round-robin bid->XCD), so each XCD caches exactly one slice -> gathers hit
// L2. Lane = (edge-subindex grp=lane>>4, dim-pair dp=lane&15): one ds_bpermute
// per 4-edge step hands each lane its edge's packed (col,val); one 4 B load
// gathers 4 edges x 64 B per instruction (same instr count / bytes as before,
// now L2-local). Row flush reduces across the 4 lane-groups (shfl_xor 16,32);
// slices write disjoint 32-dim chunks so the proven NT-store(interior) /
// atomic(first/last) ownership logic is unchanged. prep (zero-out + bf16
// convert + (col,val) pack) unchanged from R11.

#define D_FEAT 128
#define EPW 128           // edges per wave per slice (multiple of 64)
#define WAVES_PER_BLOCK 4
#define BLOCK_THREADS 256
#define NSLICE 4          // 32 dims (64 B) per slice; 3.2 MB table slice
#define PF 8              // fallback path prefetch

typedef float v2f __attribute__((ext_vector_type(2)));

__device__ __forceinline__ float bcast_f(float v, int j) {
    return __int_as_float(__builtin_amdgcn_readlane(__float_as_int(v), j));
}

__device__ __forceinline__ unsigned short f2bf_rne(float f) {
    unsigned int b = __float_as_uint(f);
    b += 0x7fffu + ((b >> 16) & 1u);
    return (unsigned short)(b >> 16);
}

// prep: zero out + x fp32->bf16 + pack (col<<16)|bf16(val).
__global__ __launch_bounds__(256) void prep_kernel(
    const float* __restrict__ x, const float* __restrict__ vals,
    const int* __restrict__ cols, unsigned short* __restrict__ xb,
    unsigned int* __restrict__ cv, float* __restrict__ out,
    int n4, int n_edges, int n_out4) {
    const int tid = blockIdx.x * blockDim.x + threadIdx.x;
    const int nth = gridDim.x * blockDim.x;
    float4 z = make_float4(0.f, 0.f, 0.f, 0.f);
    float4* __restrict__ oz = (float4*)out;
    for (int i = tid; i < n_out4; i += nth) oz[i] = z;
    const float4* __restrict__ x4 = (const float4*)x;
    ushort4* __restrict__ o4 = (ushort4*)xb;
    for (int i = tid; i < n4; i += nth) {
        float4 f = x4[i];
        ushort4 o;
        o.x = f2bf_rne(f.x);
        o.y = f2bf_rne(f.y);
        o.z = f2bf_rne(f.z);
        o.w = f2bf_rne(f.w);
        o4[i] = o;
    }
    for (int e = tid; e < n_edges; e += nth) {
        cv[e] = ((unsigned int)cols[e] << 16) | (unsigned int)f2bf_rne(vals[e]);
    }
}

__global__ __launch_bounds__(BLOCK_THREADS) void agg_sliced_kernel(
    const unsigned int* __restrict__ xb,  // [N][64] uints (2 bf16 dims each)
    const unsigned int* __restrict__ cv,  // [E] packed (col<<16)|bf16(val)
    const int* __restrict__ rows, float* __restrict__ out, int n_edges) {
    const int slice = blockIdx.x & (NSLICE - 1);   // pins slice to XCD {s,s+4}
    const int sb    = blockIdx.x >> 2;
    const int wseq  = sb * WAVES_PER_BLOCK + (threadIdx.x >> 6);
    const int lane  = threadIdx.x & 63;
    const int grp   = lane >> 4;   // edge sub-index within a 4-edge step
    const int dp    = lane & 15;   // dim-pair within this slice

    const int start = wseq * EPW;
    if (start >= n_edges) return;
    const int end = min(start + EPW, n_edges);  // %64 by host guard

    const unsigned int* __restrict__ xs = xb + (slice << 4) + dp;
    float* __restrict__ osl = out + (slice << 5) + 2 * dp;

    const int first_row = rows[start];  // wave-uniform broadcast load
    int cur_row = first_row;
    float accx = 0.f, accy = 0.f;

    // Flush: sum the 4 lane-group partials, then lanes 0..15 write 32 dims.
    auto flush_row = [&](int fr, bool force_atomic) {
        accx += __shfl_xor(accx, 16);
        accy += __shfl_xor(accy, 16);
        accx += __shfl_xor(accx, 32);
        accy += __shfl_xor(accy, 32);
        if (lane < 16) {
            float* o = osl + (size_t)fr * D_FEAT;
            if (force_atomic || fr == first_row) {
                atomicAdd(o, accx);
                atomicAdd(o + 1, accy);
            } else {
                v2f st; st.x = accx; st.y = accy;
                __builtin_nontemporal_store(st, (v2f*)o);
            }
        }
        accx = 0.f;
        accy = 0.f;
    };

    for (int e0 = start; e0 < end; e0 += 64) {
        const unsigned int mycv = __builtin_nontemporal_load(cv + e0 + lane);
        const int myr = __builtin_nontemporal_load(rows + e0 + lane);
        const int nxt = __shfl(myr, (lane + 1) & 63);
        const unsigned long long bmask =
            __ballot(myr != nxt) & 0x7fffffffffffffffULL;  // bit63 -> next grp
        const int g0 = __builtin_amdgcn_readfirstlane(myr);
        if (g0 != cur_row) {  // cur_row ended at previous group's edge #63
            flush_row(cur_row, false);
            cur_row = g0;
        }

        // Pass 1: 16 independent gathers (4 edges x 64 B each), all in flight.
        unsigned int xu[16];
        unsigned int vfu[16];
#pragma unroll
        for (int t = 0; t < 16; ++t) {
            const unsigned int ecv =
                (unsigned int)__shfl((int)mycv, (t << 2) | grp);
            xu[t] = xs[(size_t)(ecv >> 16) * (D_FEAT / 2)];
            vfu[t] = ecv << 16;  // bf16 val in high half
        }
        // Pass 2: accumulate; flush at row boundaries (ordered slow path).
#pragma unroll
        for (int t = 0; t < 16; ++t) {
            const float vf = __uint_as_float(vfu[t]);
            const float xlo = __uint_as_float(xu[t] << 16);
            const float xhi = __uint_as_float(xu[t] & 0xffff0000u);
            const unsigned int b4 =
                (unsigned int)(bmask >> (t << 2)) & 0xFu;
            if (b4 == 0u) {  // all 4 edges continue the same row
                accx = fmaf(vf, xlo, accx);
                accy = fmaf(vf, xhi, accy);
            } else {  // ordered: add group j's edge, flush where bit set
#pragma unroll
                for (int j = 0; j < 4; ++j) {
                    if (grp == j) {
                        accx = fmaf(vf, xlo, accx);
                        accy = fmaf(vf, xhi, accy);
                    }
                    if ((b4 >> j) & 1u) {
                        const int fr =
                            __builtin_amdgcn_readlane(myr, (t << 2) + j);
                        flush_row(fr, false);
                    }
                }
            }
        }
        cur_row = __builtin_amdgcn_readlane(myr, 63);
    }
    // Final row of the span: possibly shared with the next wave -> atomic.
    flush_row(cur_row, true);
}

// Fallback (R3-proven fp32 atomic path) for unexpected shapes / small ws.
__global__ __launch_bounds__(BLOCK_THREADS) void agg_f32_kernel(
    const float* __restrict__ x, const float* __restrict__ vals,
    const int* __restrict__ rows, const int* __restrict__ cols,
    float* __restrict__ out, int n_edges, int epw) {
    const int wave = blockIdx.x * WAVES_PER_BLOCK + (threadIdx.x >> 6);
    const int lane = threadIdx.x & 63;

    const int start = wave * epw;
    if (start >= n_edges) return;
    int end = start + epw;
    if (end > n_edges) end = n_edges;

    const float2* __restrict__ x2 = (const float2*)x;
    const int first_row = rows[start];
    const int last_row  = rows[end - 1];

    float2 acc = make_float2(0.f, 0.f);
    int cur_row = first_row;

    for (int e0 = start; e0 < end; e0 += 64) {
        const int nb = min(end - e0, 64);
        int myc = 0, myr = 0;
        float myv = 0.f;
        if (lane < nb) {
            myc = cols[e0 + lane];
            myr = rows[e0 + lane];
            myv = vals[e0 + lane];
        }
        for (int j0 = 0; j0 < nb; j0 += PF) {
            const int m = min(nb - j0, PF);
            float2 xv[PF];
            int    rj[PF];
            float  vj[PF];
#pragma unroll
            for (int t = 0; t < PF; ++t) {
                if (t < m) {
                    const int cj = __builtin_amdgcn_readlane(myc, j0 + t);
                    rj[t] = __builtin_amdgcn_readlane(myr, j0 + t);
                    vj[t] = bcast_f(myv, j0 + t);
                    xv[t] = x2[(size_t)cj * (D_FEAT / 2) + lane];
                }
            }
#pragma unroll
            for (int t = 0; t < PF; ++t) {
                if (t < m) {
                    if (rj[t] != cur_row) {
                        float* o = out + (size_t)cur_row * D_FEAT + 2 * lane;
                        if (cur_row == first_row || cur_row == last_row) {
                            atomicAdd(o,     acc.x);
                            atomicAdd(o + 1, acc.y);
                        } else {
                            v2f st; st.x = acc.x; st.y = acc.y;
                            __builtin_nontemporal_store(st, (v2f*)o);
                        }
                        acc.x = 0.f; acc.y = 0.f;
                        cur_row = rj[t];
                    }
                    acc.x = fmaf(vj[t], xv[t].x, acc.x);
                    acc.y = fmaf(vj[t], xv[t].y, acc.y);
                }
            }
        }
    }
    float* o = out + (size_t)cur_row * D_FEAT + 2 * lane;
    atomicAdd(o,     acc.x);
    atomicAdd(o + 1, acc.y);
}

extern "C" void kernel_launch(void* const* d_in, const int* in_sizes, int n_in,
                              void* d_out, int out_size, void* d_ws, size_t ws_size,
                              hipStream_t stream) {
    const float* x    = (const float*)d_in[0];
    const float* vals = (const float*)d_in[1];
    const int*   rows = (const int*)d_in[2];
    const int*   cols = (const int*)d_in[3];
    float*       out  = (float*)d_out;

    const int n_edges = in_sizes[1];
    const int n_x     = in_sizes[0];          // N*D floats
    const int n_nodes = out_size / D_FEAT;    // N

    const size_t xb_bytes = (size_t)n_x * sizeof(unsigned short);
    const size_t cv_off   = (xb_bytes + 255) & ~(size_t)255;
    const size_t need     = cv_off + (size_t)n_edges * sizeof(unsigned int);

    const bool fast_ok = (ws_size >= need) && (n_edges % 64 == 0) &&
                         (n_nodes <= 65536) && (n_x % 4 == 0) &&
                         (out_size % 4 == 0) && (n_x == n_nodes * D_FEAT);

    if (fast_ok) {
        unsigned short* xb = (unsigned short*)d_ws;
        unsigned int*   cv = (unsigned int*)((char*)d_ws + cv_off);
        prep_kernel<<<2048, 256, 0, stream>>>(x, vals, cols, xb, cv, out,
                                              n_x / 4, n_edges, out_size / 4);
        const int waves = (n_edges + EPW - 1) / EPW;  // per slice
        const int span_blocks = (waves + WAVES_PER_BLOCK - 1) / WAVES_PER_BLOCK;
        const int blocks = span_blocks * NSLICE;
        agg_sliced_kernel<<<blocks, BLOCK_THREADS, 0, stream>>>(
            (const unsigned int*)xb, cv, rows, out, n_edges);
    } else {
        (void)hipMemsetAsync(d_out, 0, (size_t)out_size * sizeof(float), stream);
        const int total_waves = 8192;
        const int epw    = (n_edges + total_waves - 1) / total_waves;
        const int blocks = total_waves / WAVES_PER_BLOCK;
        agg_f32_kernel<<<blocks, BLOCK_THREADS, 0, stream>>>(
            x, vals, rows, cols, out, n_edges, epw);
    }
}

// Round 5
// 126.954 us; speedup vs baseline: 1.0132x; 1.0132x over previous
//
#include <hip/hip_runtime.h>

// out = A @ x, COO (rows sorted), E=800000, N=50000, D=128.
// R13: slice-major xb layout -> true XCD-L2 residency.
// R12 post-mortem: slicing the ADDRESS space without re-laying-out the table
// gained nothing: slice s reads 64 B of every 256 B row, so at 128 B line
// granularity a "3.2 MB slice" occupies 6.4 MB of cache lines > 4 MiB L2 ->
// still thrashing (FETCH rose to 93.9 MB = +4x metadata re-read, gather
// misses unchanged; agg time flat at 47 us; VALUBusy 15.9->38.5% absorbed
// free, proving latency still governs).
// Fix: prep writes xb slice-major: xb[s][node][32 dims]; each slice is a
// CONTIGUOUS 3.2 MB region -> line footprint 3.2 MB < 4 MiB XCD-L2.
// slice = blockIdx.x & 3 pins slice s to XCDs {s, s+4} (round-robin bid->XCD)
// so each XCD caches exactly its slice; gathers become L2 hits.
// agg structure (16-lane x 4-edge gather, shfl_xor flush reduction,
// NT-store interior / atomic first+last ownership) unchanged from R12 (passed).

#define D_FEAT 128
#define EPW 128           // edges per wave per slice (multiple of 64)
#define WAVES_PER_BLOCK 4
#define BLOCK_THREADS 256
#define NSLICE 4          // 32 dims (64 B) per slice; 3.2 MB contiguous slice
#define PF 8              // fallback path prefetch

typedef float v2f __attribute__((ext_vector_type(2)));

__device__ __forceinline__ float bcast_f(float v, int j) {
    return __int_as_float(__builtin_amdgcn_readlane(__float_as_int(v), j));
}

__device__ __forceinline__ unsigned short f2bf_rne(float f) {
    unsigned int b = __float_as_uint(f);
    b += 0x7fffu + ((b >> 16) & 1u);
    return (unsigned short)(b >> 16);
}

// prep: zero out + x fp32->bf16 into SLICE-MAJOR layout + pack (col,val).
// Slice-major: xb4[s * n_nodes*8 + node*8 + k] where k indexes 8 ushort4
// (= 32 dims) of slice s. Input float4 i: node = i>>5, chunk c = i&31,
// slice = c>>3, k = c&7.
__global__ __launch_bounds__(256) void prep_kernel(
    const float* __restrict__ x, const float* __restrict__ vals,
    const int* __restrict__ cols, unsigned short* __restrict__ xb,
    unsigned int* __restrict__ cv, float* __restrict__ out,
    int n4, int n_edges, int n_out4, int n_nodes) {
    const int tid = blockIdx.x * blockDim.x + threadIdx.x;
    const int nth = gridDim.x * blockDim.x;
    float4 z = make_float4(0.f, 0.f, 0.f, 0.f);
    float4* __restrict__ oz = (float4*)out;
    for (int i = tid; i < n_out4; i += nth) oz[i] = z;
    const float4* __restrict__ x4 = (const float4*)x;
    ushort4* __restrict__ o4 = (ushort4*)xb;
    const size_t slice_stride4 = (size_t)n_nodes << 3;  // 8 ushort4 per node
    for (int i = tid; i < n4; i += nth) {
        float4 f = x4[i];
        ushort4 o;
        o.x = f2bf_rne(f.x);
        o.y = f2bf_rne(f.y);
        o.z = f2bf_rne(f.z);
        o.w = f2bf_rne(f.w);
        const int node = i >> 5;
        const int c = i & 31;
        o4[(size_t)(c >> 3) * slice_stride4 + ((size_t)node << 3) + (c & 7)] = o;
    }
    for (int e = tid; e < n_edges; e += nth) {
        cv[e] = ((unsigned int)cols[e] << 16) | (unsigned int)f2bf_rne(vals[e]);
    }
}

__global__ __launch_bounds__(BLOCK_THREADS) void agg_sliced_kernel(
    const unsigned int* __restrict__ xb,  // slice-major: [4][N][16] uints
    const unsigned int* __restrict__ cv,  // [E] packed (col<<16)|bf16(val)
    const int* __restrict__ rows, float* __restrict__ out, int n_edges,
    int n_nodes) {
    const int slice = blockIdx.x & (NSLICE - 1);   // pins slice to XCD {s,s+4}
    const int sb    = blockIdx.x >> 2;
    const int wseq  = sb * WAVES_PER_BLOCK + (threadIdx.x >> 6);
    const int lane  = threadIdx.x & 63;
    const int grp   = lane >> 4;   // edge sub-index within a 4-edge step
    const int dp    = lane & 15;   // dim-pair (uint) within this slice

    const int start = wseq * EPW;
    if (start >= n_edges) return;
    const int end = min(start + EPW, n_edges);  // %64 by host guard

    // slice's contiguous table: n_nodes rows x 16 uints (64 B)
    const unsigned int* __restrict__ xs =
        xb + (size_t)slice * ((size_t)n_nodes << 4) + dp;
    float* __restrict__ osl = out + (slice << 5) + 2 * dp;

    const int first_row = rows[start];  // wave-uniform broadcast load
    int cur_row = first_row;
    float accx = 0.f, accy = 0.f;

    // Flush: sum the 4 lane-group partials, then lanes 0..15 write 32 dims.
    auto flush_row = [&](int fr, bool force_atomic) {
        accx += __shfl_xor(accx, 16);
        accy += __shfl_xor(accy, 16);
        accx += __shfl_xor(accx, 32);
        accy += __shfl_xor(accy, 32);
        if (lane < 16) {
            float* o = osl + (size_t)fr * D_FEAT;
            if (force_atomic || fr == first_row) {
                atomicAdd(o, accx);
                atomicAdd(o + 1, accy);
            } else {
                v2f st; st.x = accx; st.y = accy;
                __builtin_nontemporal_store(st, (v2f*)o);
            }
        }
        accx = 0.f;
        accy = 0.f;
    };

    for (int e0 = start; e0 < end; e0 += 64) {
        const unsigned int mycv = __builtin_nontemporal_load(cv + e0 + lane);
        const int myr = __builtin_nontemporal_load(rows + e0 + lane);
        const int nxt = __shfl(myr, (lane + 1) & 63);
        const unsigned long long bmask =
            __ballot(myr != nxt) & 0x7fffffffffffffffULL;  // bit63 -> next grp
        const int g0 = __builtin_amdgcn_readfirstlane(myr);
        if (g0 != cur_row) {  // cur_row ended at previous group's edge #63
            flush_row(cur_row, false);
            cur_row = g0;
        }

        // Pass 1: 16 independent gathers (4 edges x 64 B each), all in flight.
        unsigned int xu[16];
        unsigned int vfu[16];
#pragma unroll
        for (int t = 0; t < 16; ++t) {
            const unsigned int ecv =
                (unsigned int)__shfl((int)mycv, (t << 2) | grp);
            xu[t] = xs[(size_t)(ecv >> 16) << 4];
            vfu[t] = ecv << 16;  // bf16 val in high half
        }
        // Pass 2: accumulate; flush at row boundaries (ordered slow path).
#pragma unroll
        for (int t = 0; t < 16; ++t) {
            const float vf = __uint_as_float(vfu[t]);
            const float xlo = __uint_as_float(xu[t] << 16);
            const float xhi = __uint_as_float(xu[t] & 0xffff0000u);
            const unsigned int b4 =
                (unsigned int)(bmask >> (t << 2)) & 0xFu;
            if (b4 == 0u) {  // all 4 edges continue the same row
                accx = fmaf(vf, xlo, accx);
                accy = fmaf(vf, xhi, accy);
            } else {  // ordered: add group j's edge, flush where bit set
#pragma unroll
                for (int j = 0; j < 4; ++j) {
                    if (grp == j) {
                        accx = fmaf(vf, xlo, accx);
                        accy = fmaf(vf, xhi, accy);
                    }
                    if ((b4 >> j) & 1u) {
                        const int fr =
                            __builtin_amdgcn_readlane(myr, (t << 2) + j);
                        flush_row(fr, false);
                    }
                }
            }
        }
        cur_row = __builtin_amdgcn_readlane(myr, 63);
    }
    // Final row of the span: possibly shared with the next wave -> atomic.
    flush_row(cur_row, true);
}

// Fallback (R3-proven fp32 atomic path) for unexpected shapes / small ws.
__global__ __launch_bounds__(BLOCK_THREADS) void agg_f32_kernel(
    const float* __restrict__ x, const float* __restrict__ vals,
    const int* __restrict__ rows, const int* __restrict__ cols,
    float* __restrict__ out, int n_edges, int epw) {
    const int wave = blockIdx.x * WAVES_PER_BLOCK + (threadIdx.x >> 6);
    const int lane = threadIdx.x & 63;

    const int start = wave * epw;
    if (start >= n_edges) return;
    int end = start + epw;
    if (end > n_edges) end = n_edges;

    const float2* __restrict__ x2 = (const float2*)x;
    const int first_row = rows[start];
    const int last_row  = rows[end - 1];

    float2 acc = make_float2(0.f, 0.f);
    int cur_row = first_row;

    for (int e0 = start; e0 < end; e0 += 64) {
        const int nb = min(end - e0, 64);
        int myc = 0, myr = 0;
        float myv = 0.f;
        if (lane < nb) {
            myc = cols[e0 + lane];
            myr = rows[e0 + lane];
            myv = vals[e0 + lane];
        }
        for (int j0 = 0; j0 < nb; j0 += PF) {
            const int m = min(nb - j0, PF);
            float2 xv[PF];
            int    rj[PF];
            float  vj[PF];
#pragma unroll
            for (int t = 0; t < PF; ++t) {
                if (t < m) {
                    const int cj = __builtin_amdgcn_readlane(myc, j0 + t);
                    rj[t] = __builtin_amdgcn_readlane(myr, j0 + t);
                    vj[t] = bcast_f(myv, j0 + t);
                    xv[t] = x2[(size_t)cj * (D_FEAT / 2) + lane];
                }
            }
#pragma unroll
            for (int t = 0; t < PF; ++t) {
                if (t < m) {
                    if (rj[t] != cur_row) {
                        float* o = out + (size_t)cur_row * D_FEAT + 2 * lane;
                        if (cur_row == first_row || cur_row == last_row) {
                            atomicAdd(o,     acc.x);
                            atomicAdd(o + 1, acc.y);
                        } else {
                            v2f st; st.x = acc.x; st.y = acc.y;
                            __builtin_nontemporal_store(st, (v2f*)o);
                        }
                        acc.x = 0.f; acc.y = 0.f;
                        cur_row = rj[t];
                    }
                    acc.x = fmaf(vj[t], xv[t].x, acc.x);
                    acc.y = fmaf(vj[t], xv[t].y, acc.y);
                }
            }
        }
    }
    float* o = out + (size_t)cur_row * D_FEAT + 2 * lane;
    atomicAdd(o,     acc.x);
    atomicAdd(o + 1, acc.y);
}

extern "C" void kernel_launch(void* const* d_in, const int* in_sizes, int n_in,
                              void* d_out, int out_size, void* d_ws, size_t ws_size,
                              hipStream_t stream) {
    const float* x    = (const float*)d_in[0];
    const float* vals = (const float*)d_in[1];
    const int*   rows = (const int*)d_in[2];
    const int*   cols = (const int*)d_in[3];
    float*       out  = (float*)d_out;

    const int n_edges = in_sizes[1];
    const int n_x     = in_sizes[0];          // N*D floats
    const int n_nodes = out_size / D_FEAT;    // N

    const size_t xb_bytes = (size_t)n_x * sizeof(unsigned short);
    const size_t cv_off   = (xb_bytes + 255) & ~(size_t)255;
    const size_t need     = cv_off + (size_t)n_edges * sizeof(unsigned int);

    const bool fast_ok = (ws_size >= need) && (n_edges % 64 == 0) &&
                         (n_nodes <= 65536) && (n_x % 4 == 0) &&
                         (out_size % 4 == 0) && (n_x == n_nodes * D_FEAT);

    if (fast_ok) {
        unsigned short* xb = (unsigned short*)d_ws;
        unsigned int*   cv = (unsigned int*)((char*)d_ws + cv_off);
        prep_kernel<<<2048, 256, 0, stream>>>(x, vals, cols, xb, cv, out,
                                              n_x / 4, n_edges, out_size / 4,
                                              n_nodes);
        const int waves = (n_edges + EPW - 1) / EPW;  // per slice
        const int span_blocks = (waves + WAVES_PER_BLOCK - 1) / WAVES_PER_BLOCK;
        const int blocks = span_blocks * NSLICE;
        agg_sliced_kernel<<<blocks, BLOCK_THREADS, 0, stream>>>(
            (const unsigned int*)xb, cv, rows, out, n_edges, n_nodes);
    } else {
        (void)hipMemsetAsync(d_out, 0, (size_t)out_size * sizeof(float), stream);
        const int total_waves = 8192;
        const int epw    = (n_edges + total_waves - 1) / total_waves;
        const int blocks = total_waves / WAVES_PER_BLOCK;
        agg_f32_kernel<<<blocks, BLOCK_THREADS, 0, stream>>>(
            x, vals, rows, cols, out, n_edges, epw);
    }
}

// Round 7
// 121.623 us; speedup vs baseline: 1.0576x; 1.0438x over previous
//
#include <hip/hip_runtime.h>

// out = A @ x, COO (rows sorted), E=800000, N=50000, D=128.
// R15 = R14 resubmitted (R14 bench failed on container acquisition, never ran).
// Forced-MLP pair-gather. R11-R13 showed agg time (~46 us) is invariant
// to gather placement (L2-sliced / L3 / HBM mix) -> not location-latency or
// byte bound. R11's agg VGPR_Count=20 exposes the real issue: the "16
// independent gathers" were rolled into a ~2-4-deep chain (16 dests don't fit
// 20 VGPRs). Kernel time ~= one wave's serial gather chain (6250 waves ~= 1.4
// resident generations). Fix: restructure for real MLP:
//  - 2 edges per instruction: lanes 0-31 = edge a's 256 B row (8 B/lane,
//    dwordx2), lanes 32-63 = edge b. Half the VMEM instrs, 2x bytes each.
//  - explicit 16-step batches with live xlo/xhi/vfu[16] arrays (~48 VGPR)
//    -> 16 x 512 B in flight per wave (vs ~1 KB before).
//  - addresses from two wave-uniform readlanes + cndmask (no bpermute in the
//    address chain).
//  - flush: shfl_xor(32) half-reduce, lanes 0-31 float4 NT store; atomic on
//    first/last rows of the span (proven ownership logic).
// prep unchanged from R11's proven linear layout (zero-out + bf16 + pack).

#define D_FEAT 128
#define EPW 128           // edges per wave (multiple of 64)
#define WAVES_PER_BLOCK 4
#define BLOCK_THREADS 256
#define PF 8              // fallback path prefetch

typedef float v2f __attribute__((ext_vector_type(2)));
typedef float v4f __attribute__((ext_vector_type(4)));

__device__ __forceinline__ float bcast_f(float v, int j) {
    return __int_as_float(__builtin_amdgcn_readlane(__float_as_int(v), j));
}

__device__ __forceinline__ unsigned short f2bf_rne(float f) {
    unsigned int b = __float_as_uint(f);
    b += 0x7fffu + ((b >> 16) & 1u);
    return (unsigned short)(b >> 16);
}

// prep: zero out + x fp32->bf16 (linear row-major) + pack (col<<16)|bf16(val).
__global__ __launch_bounds__(256) void prep_kernel(
    const float* __restrict__ x, const float* __restrict__ vals,
    const int* __restrict__ cols, unsigned short* __restrict__ xb,
    unsigned int* __restrict__ cv, float* __restrict__ out,
    int n4, int n_edges, int n_out4) {
    const int tid = blockIdx.x * blockDim.x + threadIdx.x;
    const int nth = gridDim.x * blockDim.x;
    float4 z = make_float4(0.f, 0.f, 0.f, 0.f);
    float4* __restrict__ oz = (float4*)out;
    for (int i = tid; i < n_out4; i += nth) oz[i] = z;
    const float4* __restrict__ x4 = (const float4*)x;
    ushort4* __restrict__ o4 = (ushort4*)xb;
    for (int i = tid; i < n4; i += nth) {
        float4 f = x4[i];
        ushort4 o;
        o.x = f2bf_rne(f.x);
        o.y = f2bf_rne(f.y);
        o.z = f2bf_rne(f.z);
        o.w = f2bf_rne(f.w);
        o4[i] = o;
    }
    for (int e = tid; e < n_edges; e += nth) {
        cv[e] = ((unsigned int)cols[e] << 16) | (unsigned int)f2bf_rne(vals[e]);
    }
}

__global__ __launch_bounds__(BLOCK_THREADS) void agg_pair_kernel(
    const unsigned int* __restrict__ xb,  // [N][64] uints, 2 bf16 each
    const unsigned int* __restrict__ cv,  // [E] packed (col<<16)|bf16(val)
    const int* __restrict__ rows, float* __restrict__ out, int n_edges) {
    const int wave = blockIdx.x * WAVES_PER_BLOCK + (threadIdx.x >> 6);
    const int lane = threadIdx.x & 63;
    const int half = lane >> 5;   // 0: edge a, 1: edge b of each pair
    const int sub  = lane & 31;   // 4-dim chunk within the row

    const int start = wave * EPW;
    if (start >= n_edges) return;
    const int end = min(start + EPW, n_edges);  // %64 by host guard

    const int first_row = rows[start];  // wave-uniform broadcast load
    int cur_row = first_row;
    float a0 = 0.f, a1 = 0.f, a2 = 0.f, a3 = 0.f;

    // Flush: reduce the two half-wave partials, lanes 0-31 write 4 dims each.
    auto flush_row = [&](int fr, bool force_atomic) {
        const float s0 = a0 + __shfl_xor(a0, 32);
        const float s1 = a1 + __shfl_xor(a1, 32);
        const float s2 = a2 + __shfl_xor(a2, 32);
        const float s3 = a3 + __shfl_xor(a3, 32);
        if (lane < 32) {
            float* o = out + (size_t)fr * D_FEAT + (sub << 2);
            if (force_atomic || fr == first_row) {
                atomicAdd(o, s0);
                atomicAdd(o + 1, s1);
                atomicAdd(o + 2, s2);
                atomicAdd(o + 3, s3);
            } else {
                v4f st; st.x = s0; st.y = s1; st.z = s2; st.w = s3;
                __builtin_nontemporal_store(st, (v4f*)o);
            }
        }
        a0 = 0.f; a1 = 0.f; a2 = 0.f; a3 = 0.f;
    };

#pragma unroll
    for (int e0 = start; e0 < end; e0 += 64) {
        const unsigned int mycv = __builtin_nontemporal_load(cv + e0 + lane);
        const int myr = __builtin_nontemporal_load(rows + e0 + lane);
        const int nxt = __shfl(myr, (lane + 1) & 63);
        const unsigned long long bmask =
            __ballot(myr != nxt) & 0x7fffffffffffffffULL;  // bit63 -> next grp
        const int g0 = __builtin_amdgcn_readfirstlane(myr);
        if (g0 != cur_row) {  // cur_row ended at previous group's edge #63
            flush_row(cur_row, false);
            cur_row = g0;
        }

#pragma unroll
        for (int b = 0; b < 2; ++b) {  // batch = 32 edges = 16 pair-steps
            unsigned int xlo[16], xhi[16], vfu[16];
#pragma unroll
            for (int t = 0; t < 16; ++t) {  // 16 dwordx2 gathers in flight
                const int ebase = (b << 5) + (t << 1);
                const unsigned int ea =
                    (unsigned int)__builtin_amdgcn_readlane((int)mycv, ebase);
                const unsigned int eb =
                    (unsigned int)__builtin_amdgcn_readlane((int)mycv, ebase + 1);
                const unsigned int ecv = half ? eb : ea;
                const uint2 u = *(const uint2*)(
                    xb + ((size_t)(ecv >> 16) << 6) + (sub << 1));
                xlo[t] = u.x;
                xhi[t] = u.y;
                vfu[t] = ecv << 16;  // bf16 val in high half
            }
#pragma unroll
            for (int t = 0; t < 16; ++t) {
                const float vf = __uint_as_float(vfu[t]);
                const float x0 = __uint_as_float(xlo[t] << 16);
                const float x1 = __uint_as_float(xlo[t] & 0xffff0000u);
                const float x2 = __uint_as_float(xhi[t] << 16);
                const float x3 = __uint_as_float(xhi[t] & 0xffff0000u);
                const int e2 = (b << 5) + (t << 1);
                const unsigned int b2 = (unsigned int)(bmask >> e2) & 3u;
                if (b2 == 0u) {  // both edges continue the same row
                    a0 = fmaf(vf, x0, a0);
                    a1 = fmaf(vf, x1, a1);
                    a2 = fmaf(vf, x2, a2);
                    a3 = fmaf(vf, x3, a3);
                } else {  // ordered: edge a, maybe flush, edge b, maybe flush
                    if (half == 0) {
                        a0 = fmaf(vf, x0, a0);
                        a1 = fmaf(vf, x1, a1);
                        a2 = fmaf(vf, x2, a2);
                        a3 = fmaf(vf, x3, a3);
                    }
                    if (b2 & 1u)
                        flush_row(__builtin_amdgcn_readlane(myr, e2), false);
                    if (half == 1) {
                        a0 = fmaf(vf, x0, a0);
                        a1 = fmaf(vf, x1, a1);
                        a2 = fmaf(vf, x2, a2);
                        a3 = fmaf(vf, x3, a3);
                    }
                    if (b2 & 2u)
                        flush_row(__builtin_amdgcn_readlane(myr, e2 + 1), false);
                }
            }
        }
        cur_row = __builtin_amdgcn_readlane(myr, 63);
    }
    // Final row of the span: possibly shared with the next wave -> atomic.
    flush_row(cur_row, true);
}

// Fallback (R3-proven fp32 atomic path) for unexpected shapes / small ws.
__global__ __launch_bounds__(BLOCK_THREADS) void agg_f32_kernel(
    const float* __restrict__ x, const float* __restrict__ vals,
    const int* __restrict__ rows, const int* __restrict__ cols,
    float* __restrict__ out, int n_edges, int epw) {
    const int wave = blockIdx.x * WAVES_PER_BLOCK + (threadIdx.x >> 6);
    const int lane = threadIdx.x & 63;

    const int start = wave * epw;
    if (start >= n_edges) return;
    int end = start + epw;
    if (end > n_edges) end = n_edges;

    const float2* __restrict__ x2 = (const float2*)x;
    const int first_row = rows[start];
    const int last_row  = rows[end - 1];

    float2 acc = make_float2(0.f, 0.f);
    int cur_row = first_row;

    for (int e0 = start; e0 < end; e0 += 64) {
        const int nb = min(end - e0, 64);
        int myc = 0, myr = 0;
        float myv = 0.f;
        if (lane < nb) {
            myc = cols[e0 + lane];
            myr = rows[e0 + lane];
            myv = vals[e0 + lane];
        }
        for (int j0 = 0; j0 < nb; j0 += PF) {
            const int m = min(nb - j0, PF);
            float2 xv[PF];
            int    rj[PF];
            float  vj[PF];
#pragma unroll
            for (int t = 0; t < PF; ++t) {
                if (t < m) {
                    const int cj = __builtin_amdgcn_readlane(myc, j0 + t);
                    rj[t] = __builtin_amdgcn_readlane(myr, j0 + t);
                    vj[t] = bcast_f(myv, j0 + t);
                    xv[t] = x2[(size_t)cj * (D_FEAT / 2) + lane];
                }
            }
#pragma unroll
            for (int t = 0; t < PF; ++t) {
                if (t < m) {
                    if (rj[t] != cur_row) {
                        float* o = out + (size_t)cur_row * D_FEAT + 2 * lane;
                        if (cur_row == first_row || cur_row == last_row) {
                            atomicAdd(o,     acc.x);
                            atomicAdd(o + 1, acc.y);
                        } else {
                            v2f st; st.x = acc.x; st.y = acc.y;
                            __builtin_nontemporal_store(st, (v2f*)o);
                        }
                        acc.x = 0.f; acc.y = 0.f;
                        cur_row = rj[t];
                    }
                    acc.x = fmaf(vj[t], xv[t].x, acc.x);
                    acc.y = fmaf(vj[t], xv[t].y, acc.y);
                }
            }
        }
    }
    float* o = out + (size_t)cur_row * D_FEAT + 2 * lane;
    atomicAdd(o,     acc.x);
    atomicAdd(o + 1, acc.y);
}

extern "C" void kernel_launch(void* const* d_in, const int* in_sizes, int n_in,
                              void* d_out, int out_size, void* d_ws, size_t ws_size,
                              hipStream_t stream) {
    const float* x    = (const float*)d_in[0];
    const float* vals = (const float*)d_in[1];
    const int*   rows = (const int*)d_in[2];
    const int*   cols = (const int*)d_in[3];
    float*       out  = (float*)d_out;

    const int n_edges = in_sizes[1];
    const int n_x     = in_sizes[0];          // N*D floats
    const int n_nodes = out_size / D_FEAT;    // N

    const size_t xb_bytes = (size_t)n_x * sizeof(unsigned short);
    const size_t cv_off   = (xb_bytes + 255) & ~(size_t)255;
    const size_t need     = cv_off + (size_t)n_edges * sizeof(unsigned int);

    const bool fast_ok = (ws_size >= need) && (n_edges % 64 == 0) &&
                         (n_nodes <= 65536) && (n_x % 4 == 0) &&
                         (out_size % 4 == 0) && (n_x == n_nodes * D_FEAT);

    if (fast_ok) {
        unsigned short* xb = (unsigned short*)d_ws;
        unsigned int*   cv = (unsigned int*)((char*)d_ws + cv_off);
        prep_kernel<<<2048, 256, 0, stream>>>(x, vals, cols, xb, cv, out,
                                              n_x / 4, n_edges, out_size / 4);
        const int waves  = (n_edges + EPW - 1) / EPW;
        const int blocks = (waves + WAVES_PER_BLOCK - 1) / WAVES_PER_BLOCK;
        agg_pair_kernel<<<blocks, BLOCK_THREADS, 0, stream>>>(
            (const unsigned int*)xb, cv, rows, out, n_edges);
    } else {
        (void)hipMemsetAsync(d_out, 0, (size_t)out_size * sizeof(float), stream);
        const int total_waves = 8192;
        const int epw    = (n_edges + total_waves - 1) / total_waves;
        const int blocks = total_waves / WAVES_PER_BLOCK;
        agg_f32_kernel<<<blocks, BLOCK_THREADS, 0, stream>>>(
            x, vals, rows, cols, out, n_edges, epw);
    }
}